// Round 1
// baseline (806.757 us; speedup 1.0000x reference)
//
#include <hip/hip_runtime.h>
#include <hip/hip_bf16.h>
#include <stdint.h>

#define N_NODES 100000
#define N_EDGES 1600000

typedef __bf16 bf16x8 __attribute__((ext_vector_type(8)));
typedef float f32x4 __attribute__((ext_vector_type(4)));
typedef unsigned short u16;

__device__ __forceinline__ u16 f2b(float f) {
    uint32_t u = __builtin_bit_cast(uint32_t, f);
    uint32_t r = (u + 0x7fffu + ((u >> 16) & 1u)) >> 16;
    return (u16)r;
}
__device__ __forceinline__ float b2f(uint32_t lo16) {
    return __builtin_bit_cast(float, lo16 << 16);
}

// ---- setup: degree + per-dst edge counts ----
__global__ void edge_pass1(const int* __restrict__ dstp, const float* __restrict__ w,
                           float* __restrict__ deg, int* __restrict__ cnt) {
    int e = blockIdx.x * 256 + threadIdx.x;
    if (e >= N_EDGES) return;
    int d = dstp[e];
    atomicAdd(&deg[d], w[e]);
    atomicAdd(&cnt[d], 1);
}

__global__ void dinv_kernel(float* __restrict__ deg) {
    int i = blockIdx.x * 256 + threadIdx.x;
    if (i >= N_NODES) return;
    float dg = deg[i];
    deg[i] = (dg > 0.f) ? rsqrtf(fmaxf(dg, 1e-30f)) : 0.f;
}

// single-block exclusive scan of cnt -> row_ptr (and copy to nxt)
__global__ __launch_bounds__(1024) void scan_kernel(const int* __restrict__ cnt,
                                                    int* __restrict__ row_ptr,
                                                    int* __restrict__ nxt) {
    __shared__ int wsum[16];
    int t = threadIdx.x;
    int lane = t & 63, wid = t >> 6;
    int carry = 0;
    for (int base = 0; base < N_NODES; base += 4096) {
        int idx = base + t * 4;
        int v0 = (idx + 0 < N_NODES) ? cnt[idx + 0] : 0;
        int v1 = (idx + 1 < N_NODES) ? cnt[idx + 1] : 0;
        int v2 = (idx + 2 < N_NODES) ? cnt[idx + 2] : 0;
        int v3 = (idx + 3 < N_NODES) ? cnt[idx + 3] : 0;
        int s1 = v0 + v1, s2 = s1 + v2, tot = s2 + v3;
        int x = tot;
        #pragma unroll
        for (int off = 1; off < 64; off <<= 1) {
            int y = __shfl_up(x, off, 64);
            if (lane >= off) x += y;
        }
        if (lane == 63) wsum[wid] = x;
        __syncthreads();
        int woff = carry;
        for (int j = 0; j < wid; j++) woff += wsum[j];
        int excl = woff + x - tot;
        if (idx + 0 < N_NODES) { row_ptr[idx + 0] = excl;      nxt[idx + 0] = excl; }
        if (idx + 1 < N_NODES) { row_ptr[idx + 1] = excl + v0; nxt[idx + 1] = excl + v0; }
        if (idx + 2 < N_NODES) { row_ptr[idx + 2] = excl + s1; nxt[idx + 2] = excl + s1; }
        if (idx + 3 < N_NODES) { row_ptr[idx + 3] = excl + s2; nxt[idx + 3] = excl + s2; }
        int ct = 0;
        for (int j = 0; j < 16; j++) ct += wsum[j];
        carry += ct;
        __syncthreads();
    }
    if (t == 0) row_ptr[N_NODES] = carry;
}

// scatter edges into CSR slots; compute norm = dinv[src]*w*dinv[dst]
__global__ void edge_pass2(const int* __restrict__ srcp, const int* __restrict__ dstp,
                           const float* __restrict__ w, const float* __restrict__ dinv,
                           int* __restrict__ nxt, int* __restrict__ csr_src,
                           float* __restrict__ csr_norm) {
    int e = blockIdx.x * 256 + threadIdx.x;
    if (e >= N_EDGES) return;
    int s = srcp[e], d = dstp[e];
    int pos = atomicAdd(&nxt[d], 1);
    csr_src[pos] = s;
    csr_norm[pos] = dinv[s] * w[e] * dinv[d];
}

// ---- conversions ----
__global__ void conv_f32_bf16(const float* __restrict__ in, u16* __restrict__ out, int n4) {
    int i = blockIdx.x * 256 + threadIdx.x;
    if (i >= n4) return;
    float4 v = ((const float4*)in)[i];
    ushort4 o;
    o.x = f2b(v.x); o.y = f2b(v.y); o.z = f2b(v.z); o.w = f2b(v.w);
    ((ushort4*)out)[i] = o;
}

// W [K x Dout] fp32 row-major -> Wt [Dout x K] bf16 (K-contiguous for B-fragment loads)
__global__ void conv_w_transpose(const float* __restrict__ W, u16* __restrict__ Wt,
                                 int K, int Dout) {
    int i = blockIdx.x * 256 + threadIdx.x;
    if (i >= K * Dout) return;
    int k = i / Dout, n = i % Dout;
    Wt[n * K + k] = f2b(W[i]);
}

// ---- GEMM: C[N x Dout] = A[N x 128] @ W[128 x Dout], bf16 in, bf16 out ----
// one wave computes 16 rows x Dout cols; K=128 -> 4 MFMA per 16-col tile
__global__ __launch_bounds__(256) void gemm_bf16(const u16* __restrict__ A,
                                                 const u16* __restrict__ Bt,
                                                 u16* __restrict__ C, int Dout) {
    int wid = (blockIdx.x * 256 + threadIdx.x) >> 6;
    if (wid >= N_NODES / 16) return;
    int lane = threadIdx.x & 63;
    int m = lane & 15;
    int k0 = (lane >> 4) * 8;
    int r0 = wid * 16;
    const u16* ap = A + (size_t)(r0 + m) * 128 + k0;
    bf16x8 a0 = *(const bf16x8*)(ap + 0);
    bf16x8 a1 = *(const bf16x8*)(ap + 32);
    bf16x8 a2 = *(const bf16x8*)(ap + 64);
    bf16x8 a3 = *(const bf16x8*)(ap + 96);
    int ntiles = Dout >> 4;
    int rbase = r0 + ((lane >> 4) << 2);
    for (int tn = 0; tn < ntiles; tn++) {
        const u16* bp = Bt + (size_t)(tn * 16 + m) * 128 + k0;
        f32x4 acc = {0.f, 0.f, 0.f, 0.f};
        acc = __builtin_amdgcn_mfma_f32_16x16x32_bf16(a0, *(const bf16x8*)(bp + 0),  acc, 0, 0, 0);
        acc = __builtin_amdgcn_mfma_f32_16x16x32_bf16(a1, *(const bf16x8*)(bp + 32), acc, 0, 0, 0);
        acc = __builtin_amdgcn_mfma_f32_16x16x32_bf16(a2, *(const bf16x8*)(bp + 64), acc, 0, 0, 0);
        acc = __builtin_amdgcn_mfma_f32_16x16x32_bf16(a3, *(const bf16x8*)(bp + 96), acc, 0, 0, 0);
        int col = tn * 16 + m;
        #pragma unroll
        for (int i2 = 0; i2 < 4; i2++)
            C[(size_t)(rbase + i2) * Dout + col] = f2b(acc[i2]);
    }
}

// ---- aggregation: one wave per destination node, dim 128 (2 cols/lane) ----
__global__ __launch_bounds__(256) void agg128(const u16* __restrict__ H,
                                              const int* __restrict__ row_ptr,
                                              const int* __restrict__ csr_src,
                                              const float* __restrict__ csr_norm,
                                              const float* __restrict__ bias,
                                              u16* __restrict__ out, int do_relu) {
    int node = (blockIdx.x * 256 + threadIdx.x) >> 6;
    if (node >= N_NODES) return;
    int lane = threadIdx.x & 63;
    int c = lane * 2;
    float a0 = 0.f, a1 = 0.f;
    int jb = row_ptr[node], je = row_ptr[node + 1];
    int j = jb;
    for (; j + 1 < je; j += 2) {
        int s0 = csr_src[j], s1 = csr_src[j + 1];
        float w0 = csr_norm[j], w1 = csr_norm[j + 1];
        uint32_t p0 = *(const uint32_t*)(H + (size_t)s0 * 128 + c);
        uint32_t p1 = *(const uint32_t*)(H + (size_t)s1 * 128 + c);
        a0 += w0 * b2f(p0 & 0xffffu) + w1 * b2f(p1 & 0xffffu);
        a1 += w0 * b2f(p0 >> 16)     + w1 * b2f(p1 >> 16);
    }
    if (j < je) {
        int s0 = csr_src[j];
        float w0 = csr_norm[j];
        uint32_t p0 = *(const uint32_t*)(H + (size_t)s0 * 128 + c);
        a0 += w0 * b2f(p0 & 0xffffu);
        a1 += w0 * b2f(p0 >> 16);
    }
    a0 += bias[c]; a1 += bias[c + 1];
    if (do_relu) { a0 = fmaxf(a0, 0.f); a1 = fmaxf(a1, 0.f); }
    uint32_t o = (uint32_t)f2b(a0) | ((uint32_t)f2b(a1) << 16);
    *(uint32_t*)(out + (size_t)node * 128 + c) = o;
}

// ---- final aggregation: dim 64, fp32 output written twice (tuple (h,h)) ----
__global__ __launch_bounds__(256) void agg64_out(const u16* __restrict__ H,
                                                 const int* __restrict__ row_ptr,
                                                 const int* __restrict__ csr_src,
                                                 const float* __restrict__ csr_norm,
                                                 const float* __restrict__ bias,
                                                 float* __restrict__ out) {
    int node = (blockIdx.x * 256 + threadIdx.x) >> 6;
    if (node >= N_NODES) return;
    int lane = threadIdx.x & 63;
    float a = 0.f;
    int jb = row_ptr[node], je = row_ptr[node + 1];
    int j = jb;
    for (; j + 1 < je; j += 2) {
        int s0 = csr_src[j], s1 = csr_src[j + 1];
        float w0 = csr_norm[j], w1 = csr_norm[j + 1];
        float v0 = b2f((uint32_t)H[(size_t)s0 * 64 + lane]);
        float v1 = b2f((uint32_t)H[(size_t)s1 * 64 + lane]);
        a += w0 * v0 + w1 * v1;
    }
    if (j < je) {
        a += csr_norm[j] * b2f((uint32_t)H[(size_t)csr_src[j] * 64 + lane]);
    }
    a += bias[lane];
    size_t o = (size_t)node * 64 + lane;
    out[o] = a;
    out[(size_t)N_NODES * 64 + o] = a;
}

extern "C" void kernel_launch(void* const* d_in, const int* in_sizes, int n_in,
                              void* d_out, int out_size, void* d_ws, size_t ws_size,
                              hipStream_t stream) {
    const float* x  = (const float*)d_in[0];
    const int* eidx = (const int*)d_in[1];
    const float* ew = (const float*)d_in[2];
    const float* W1 = (const float*)d_in[3];
    const float* b1 = (const float*)d_in[4];
    const float* W2 = (const float*)d_in[5];
    const float* b2 = (const float*)d_in[6];
    const float* W3 = (const float*)d_in[7];
    const float* b3 = (const float*)d_in[8];
    const int* srcp = eidx;
    const int* dstp = eidx + N_EDGES;

    char* ws = (char*)d_ws;
    size_t off = 0;
    auto alloc = [&](size_t bytes) -> void* {
        void* p = ws + off;
        off += (bytes + 255) & ~(size_t)255;
        return p;
    };
    float* deg    = (float*)alloc((size_t)N_NODES * 4);
    int*   cnt    = (int*)  alloc((size_t)N_NODES * 4);
    int*   rowptr = (int*)  alloc((size_t)(N_NODES + 1) * 4);
    int*   nxt    = (int*)  alloc((size_t)N_NODES * 4);
    int*   csr_s  = (int*)  alloc((size_t)N_EDGES * 4);
    float* csr_w  = (float*)alloc((size_t)N_EDGES * 4);
    u16*   Wt1    = (u16*)  alloc(128 * 128 * 2);
    u16*   Wt2    = (u16*)  alloc(128 * 128 * 2);
    u16*   Wt3    = (u16*)  alloc(128 * 64 * 2);
    u16*   bufA   = (u16*)  alloc((size_t)N_NODES * 128 * 2);
    u16*   bufB   = (u16*)  alloc((size_t)N_NODES * 128 * 2);

    // zero deg + cnt (contiguous at ws start: 400128 + 400000 bytes)
    hipMemsetAsync(ws, 0, 800128, stream);

    edge_pass1<<<N_EDGES / 256, 256, 0, stream>>>(dstp, ew, deg, cnt);
    dinv_kernel<<<(N_NODES + 255) / 256, 256, 0, stream>>>(deg);
    scan_kernel<<<1, 1024, 0, stream>>>(cnt, rowptr, nxt);
    edge_pass2<<<N_EDGES / 256, 256, 0, stream>>>(srcp, dstp, ew, deg, nxt, csr_s, csr_w);

    conv_f32_bf16<<<(N_NODES * 128 / 4) / 256, 256, 0, stream>>>(x, bufB, N_NODES * 128 / 4);
    conv_w_transpose<<<64, 256, 0, stream>>>(W1, Wt1, 128, 128);
    conv_w_transpose<<<64, 256, 0, stream>>>(W2, Wt2, 128, 128);
    conv_w_transpose<<<32, 256, 0, stream>>>(W3, Wt3, 128, 64);

    int gemm_blocks = (N_NODES / 16 + 3) / 4;  // 4 waves/block
    // layer 1
    gemm_bf16<<<gemm_blocks, 256, 0, stream>>>(bufB, Wt1, bufA, 128);
    agg128<<<N_NODES / 4, 256, 0, stream>>>(bufA, rowptr, csr_s, csr_w, b1, bufB, 1);
    // layer 2
    gemm_bf16<<<gemm_blocks, 256, 0, stream>>>(bufB, Wt2, bufA, 128);
    agg128<<<N_NODES / 4, 256, 0, stream>>>(bufA, rowptr, csr_s, csr_w, b2, bufB, 1);
    // layer 3
    gemm_bf16<<<gemm_blocks, 256, 0, stream>>>(bufB, Wt3, bufA, 64);
    agg64_out<<<N_NODES / 4, 256, 0, stream>>>(bufA, rowptr, csr_s, csr_w, b3, (float*)d_out);
}

// Round 2
// 601.036 us; speedup vs baseline: 1.3423x; 1.3423x over previous
//
#include <hip/hip_runtime.h>
#include <hip/hip_bf16.h>
#include <stdint.h>

#define N_NODES 100000
#define N_EDGES 1600000
#define SCAN_NB 98   // ceil(100000/1024)

typedef __bf16 bf16x8 __attribute__((ext_vector_type(8)));
typedef float f32x4 __attribute__((ext_vector_type(4)));
typedef unsigned short u16;

__device__ __forceinline__ u16 f2b(float f) {
    uint32_t u = __builtin_bit_cast(uint32_t, f);
    uint32_t r = (u + 0x7fffu + ((u >> 16) & 1u)) >> 16;
    return (u16)r;
}
__device__ __forceinline__ float b2f(uint32_t lo16) {
    return __builtin_bit_cast(float, lo16 << 16);
}

// ---- pass 1: per-dst counts + per-edge rank (the ONLY atomic pass) ----
__global__ void rank_kernel(const int* __restrict__ dstp, int* __restrict__ cnt,
                            u16* __restrict__ rank) {
    int e = blockIdx.x * 256 + threadIdx.x;
    if (e >= N_EDGES) return;
    rank[e] = (u16)atomicAdd(&cnt[dstp[e]], 1);
}

// ---- 3-phase parallel exclusive scan: cnt -> rowptr ----
__global__ __launch_bounds__(1024) void scan1(const int* __restrict__ cnt,
                                              int* __restrict__ rowptr,
                                              int* __restrict__ bsum) {
    __shared__ int ws[16];
    int t = threadIdx.x;
    int i = blockIdx.x * 1024 + t;
    int lane = t & 63, wid = t >> 6;
    int v = (i < N_NODES) ? cnt[i] : 0;
    int x = v;
    #pragma unroll
    for (int off = 1; off < 64; off <<= 1) {
        int y = __shfl_up(x, off, 64);
        if (lane >= off) x += y;
    }
    if (lane == 63) ws[wid] = x;
    __syncthreads();
    int woff = 0;
    for (int j = 0; j < wid; j++) woff += ws[j];
    if (i < N_NODES) rowptr[i] = woff + x - v;
    if (t == 1023) bsum[blockIdx.x] = woff + x;
}

__global__ void scan2(const int* __restrict__ bsum, int* __restrict__ boff,
                      int* __restrict__ rowptr) {
    int lane = threadIdx.x;  // 64 threads, 1 block
    int carry = 0;
    for (int base = 0; base < SCAN_NB; base += 64) {
        int b = base + lane;
        int v = (b < SCAN_NB) ? bsum[b] : 0;
        int x = v;
        #pragma unroll
        for (int off = 1; off < 64; off <<= 1) {
            int y = __shfl_up(x, off, 64);
            if (lane >= off) x += y;
        }
        if (b < SCAN_NB) boff[b] = carry + x - v;
        carry += __shfl(x, 63, 64);
    }
    if (lane == 0) rowptr[N_NODES] = carry;
}

__global__ __launch_bounds__(1024) void scan3(int* __restrict__ rowptr,
                                              const int* __restrict__ boff) {
    int i = blockIdx.x * 1024 + threadIdx.x;
    if (i < N_NODES) rowptr[i] += boff[blockIdx.x];
}

// ---- pass 2: atomic-free CSR scatter ----
__global__ void scatter_kernel(const int* __restrict__ srcp, const int* __restrict__ dstp,
                               const float* __restrict__ w, const int* __restrict__ rowptr,
                               const u16* __restrict__ rank, int* __restrict__ csr_s,
                               float* __restrict__ csr_w) {
    int e = blockIdx.x * 256 + threadIdx.x;
    if (e >= N_EDGES) return;
    int pos = rowptr[dstp[e]] + (int)rank[e];
    csr_s[pos] = srcp[e];
    csr_w[pos] = w[e];
}

// ---- deg via per-node contiguous reduction (no atomics) -> dinv in place ----
__global__ __launch_bounds__(256) void deg_kernel(const float* __restrict__ csr_w,
                                                  const int* __restrict__ rowptr,
                                                  float* __restrict__ dinv) {
    int node = (blockIdx.x * 256 + threadIdx.x) >> 6;
    if (node >= N_NODES) return;
    int lane = threadIdx.x & 63;
    int jb = rowptr[node], je = rowptr[node + 1];
    float s = 0.f;
    for (int j = jb + lane; j < je; j += 64) s += csr_w[j];
    #pragma unroll
    for (int off = 32; off; off >>= 1) s += __shfl_down(s, off, 64);
    if (lane == 0) dinv[node] = (s > 0.f) ? rsqrtf(fmaxf(s, 1e-30f)) : 0.f;
}

// ---- fold dinv[src] into csr_w (dinv[dst] applied in agg epilogue) ----
__global__ __launch_bounds__(256) void norm_kernel(const int* __restrict__ csr_s,
                                                   float* __restrict__ csr_w,
                                                   const float* __restrict__ dinv,
                                                   const int* __restrict__ rowptr) {
    int node = (blockIdx.x * 256 + threadIdx.x) >> 6;
    if (node >= N_NODES) return;
    int lane = threadIdx.x & 63;
    int jb = rowptr[node], je = rowptr[node + 1];
    for (int j = jb + lane; j < je; j += 64) csr_w[j] *= dinv[csr_s[j]];
}

// ---- conversions ----
__global__ void conv_f32_bf16(const float* __restrict__ in, u16* __restrict__ out, int n4) {
    int i = blockIdx.x * 256 + threadIdx.x;
    if (i >= n4) return;
    float4 v = ((const float4*)in)[i];
    ushort4 o;
    o.x = f2b(v.x); o.y = f2b(v.y); o.z = f2b(v.z); o.w = f2b(v.w);
    ((ushort4*)out)[i] = o;
}

__global__ void conv_w_transpose(const float* __restrict__ W, u16* __restrict__ Wt,
                                 int K, int Dout) {
    int i = blockIdx.x * 256 + threadIdx.x;
    if (i >= K * Dout) return;
    int k = i / Dout, n = i % Dout;
    Wt[n * K + k] = f2b(W[i]);
}

// ---- GEMM: C[N x Dout] = A[N x 128] @ W[128 x Dout], bf16 in/out ----
__global__ __launch_bounds__(256) void gemm_bf16(const u16* __restrict__ A,
                                                 const u16* __restrict__ Bt,
                                                 u16* __restrict__ C, int Dout) {
    int wid = (blockIdx.x * 256 + threadIdx.x) >> 6;
    if (wid >= N_NODES / 16) return;
    int lane = threadIdx.x & 63;
    int m = lane & 15;
    int k0 = (lane >> 4) * 8;
    int r0 = wid * 16;
    const u16* ap = A + (size_t)(r0 + m) * 128 + k0;
    bf16x8 a0 = *(const bf16x8*)(ap + 0);
    bf16x8 a1 = *(const bf16x8*)(ap + 32);
    bf16x8 a2 = *(const bf16x8*)(ap + 64);
    bf16x8 a3 = *(const bf16x8*)(ap + 96);
    int ntiles = Dout >> 4;
    int rbase = r0 + ((lane >> 4) << 2);
    for (int tn = 0; tn < ntiles; tn++) {
        const u16* bp = Bt + (size_t)(tn * 16 + m) * 128 + k0;
        f32x4 acc = {0.f, 0.f, 0.f, 0.f};
        acc = __builtin_amdgcn_mfma_f32_16x16x32_bf16(a0, *(const bf16x8*)(bp + 0),  acc, 0, 0, 0);
        acc = __builtin_amdgcn_mfma_f32_16x16x32_bf16(a1, *(const bf16x8*)(bp + 32), acc, 0, 0, 0);
        acc = __builtin_amdgcn_mfma_f32_16x16x32_bf16(a2, *(const bf16x8*)(bp + 64), acc, 0, 0, 0);
        acc = __builtin_amdgcn_mfma_f32_16x16x32_bf16(a3, *(const bf16x8*)(bp + 96), acc, 0, 0, 0);
        int col = tn * 16 + m;
        #pragma unroll
        for (int i2 = 0; i2 < 4; i2++)
            C[(size_t)(rbase + i2) * Dout + col] = f2b(acc[i2]);
    }
}

// ---- aggregation dim=128: one wave per dst node, 2 cols/lane, unroll 4 ----
__global__ __launch_bounds__(256) void agg128(const u16* __restrict__ H,
                                              const int* __restrict__ row_ptr,
                                              const int* __restrict__ csr_src,
                                              const float* __restrict__ csr_w,
                                              const float* __restrict__ dinv,
                                              const float* __restrict__ bias,
                                              u16* __restrict__ out, int do_relu) {
    int node = (blockIdx.x * 256 + threadIdx.x) >> 6;
    if (node >= N_NODES) return;
    int lane = threadIdx.x & 63;
    int c = lane * 2;
    float a0 = 0.f, a1 = 0.f;
    int jb = row_ptr[node], je = row_ptr[node + 1];
    int j = jb;
    for (; j + 3 < je; j += 4) {
        int s0 = csr_src[j], s1 = csr_src[j + 1], s2 = csr_src[j + 2], s3 = csr_src[j + 3];
        float w0 = csr_w[j], w1 = csr_w[j + 1], w2 = csr_w[j + 2], w3 = csr_w[j + 3];
        uint32_t p0 = *(const uint32_t*)(H + (size_t)s0 * 128 + c);
        uint32_t p1 = *(const uint32_t*)(H + (size_t)s1 * 128 + c);
        uint32_t p2 = *(const uint32_t*)(H + (size_t)s2 * 128 + c);
        uint32_t p3 = *(const uint32_t*)(H + (size_t)s3 * 128 + c);
        a0 += w0 * b2f(p0 & 0xffffu) + w1 * b2f(p1 & 0xffffu)
            + w2 * b2f(p2 & 0xffffu) + w3 * b2f(p3 & 0xffffu);
        a1 += w0 * b2f(p0 >> 16) + w1 * b2f(p1 >> 16)
            + w2 * b2f(p2 >> 16) + w3 * b2f(p3 >> 16);
    }
    for (; j < je; j++) {
        int s0 = csr_src[j];
        float w0 = csr_w[j];
        uint32_t p0 = *(const uint32_t*)(H + (size_t)s0 * 128 + c);
        a0 += w0 * b2f(p0 & 0xffffu);
        a1 += w0 * b2f(p0 >> 16);
    }
    float dv = dinv[node];
    a0 = dv * a0 + bias[c];
    a1 = dv * a1 + bias[c + 1];
    if (do_relu) { a0 = fmaxf(a0, 0.f); a1 = fmaxf(a1, 0.f); }
    uint32_t o = (uint32_t)f2b(a0) | ((uint32_t)f2b(a1) << 16);
    *(uint32_t*)(out + (size_t)node * 128 + c) = o;
}

// ---- final aggregation dim=64, fp32 output written twice (tuple (h,h)) ----
__global__ __launch_bounds__(256) void agg64_out(const u16* __restrict__ H,
                                                 const int* __restrict__ row_ptr,
                                                 const int* __restrict__ csr_src,
                                                 const float* __restrict__ csr_w,
                                                 const float* __restrict__ dinv,
                                                 const float* __restrict__ bias,
                                                 float* __restrict__ out) {
    int node = (blockIdx.x * 256 + threadIdx.x) >> 6;
    if (node >= N_NODES) return;
    int lane = threadIdx.x & 63;
    float a = 0.f;
    int jb = row_ptr[node], je = row_ptr[node + 1];
    int j = jb;
    for (; j + 3 < je; j += 4) {
        int s0 = csr_src[j], s1 = csr_src[j + 1], s2 = csr_src[j + 2], s3 = csr_src[j + 3];
        float w0 = csr_w[j], w1 = csr_w[j + 1], w2 = csr_w[j + 2], w3 = csr_w[j + 3];
        float v0 = b2f((uint32_t)H[(size_t)s0 * 64 + lane]);
        float v1 = b2f((uint32_t)H[(size_t)s1 * 64 + lane]);
        float v2 = b2f((uint32_t)H[(size_t)s2 * 64 + lane]);
        float v3 = b2f((uint32_t)H[(size_t)s3 * 64 + lane]);
        a += w0 * v0 + w1 * v1 + w2 * v2 + w3 * v3;
    }
    for (; j < je; j++) {
        a += csr_w[j] * b2f((uint32_t)H[(size_t)csr_src[j] * 64 + lane]);
    }
    a = dinv[node] * a + bias[lane];
    size_t o = (size_t)node * 64 + lane;
    out[o] = a;
    out[(size_t)N_NODES * 64 + o] = a;
}

extern "C" void kernel_launch(void* const* d_in, const int* in_sizes, int n_in,
                              void* d_out, int out_size, void* d_ws, size_t ws_size,
                              hipStream_t stream) {
    const float* x  = (const float*)d_in[0];
    const int* eidx = (const int*)d_in[1];
    const float* ew = (const float*)d_in[2];
    const float* W1 = (const float*)d_in[3];
    const float* b1 = (const float*)d_in[4];
    const float* W2 = (const float*)d_in[5];
    const float* b2 = (const float*)d_in[6];
    const float* W3 = (const float*)d_in[7];
    const float* b3 = (const float*)d_in[8];
    const int* srcp = eidx;
    const int* dstp = eidx + N_EDGES;

    char* ws = (char*)d_ws;
    size_t off = 0;
    auto alloc = [&](size_t bytes) -> void* {
        void* p = ws + off;
        off += (bytes + 255) & ~(size_t)255;
        return p;
    };
    int*   cnt    = (int*)  alloc((size_t)N_NODES * 4);        // must be zeroed
    int*   rowptr = (int*)  alloc((size_t)(N_NODES + 1) * 4);
    int*   bsum   = (int*)  alloc(SCAN_NB * 4);
    int*   boff   = (int*)  alloc(SCAN_NB * 4);
    u16*   rank   = (u16*)  alloc((size_t)N_EDGES * 2);
    int*   csr_s  = (int*)  alloc((size_t)N_EDGES * 4);
    float* csr_w  = (float*)alloc((size_t)N_EDGES * 4);
    float* dinv   = (float*)alloc((size_t)N_NODES * 4);
    u16*   Wt1    = (u16*)  alloc(128 * 128 * 2);
    u16*   Wt2    = (u16*)  alloc(128 * 128 * 2);
    u16*   Wt3    = (u16*)  alloc(128 * 64 * 2);
    u16*   bufA   = (u16*)  alloc((size_t)N_NODES * 128 * 2);
    u16*   bufB   = (u16*)  alloc((size_t)N_NODES * 128 * 2);

    hipMemsetAsync(cnt, 0, (size_t)N_NODES * 4, stream);

    rank_kernel<<<N_EDGES / 256, 256, 0, stream>>>(dstp, cnt, rank);
    scan1<<<SCAN_NB, 1024, 0, stream>>>(cnt, rowptr, bsum);
    scan2<<<1, 64, 0, stream>>>(bsum, boff, rowptr);
    scan3<<<SCAN_NB, 1024, 0, stream>>>(rowptr, boff);
    scatter_kernel<<<N_EDGES / 256, 256, 0, stream>>>(srcp, dstp, ew, rowptr, rank, csr_s, csr_w);
    deg_kernel<<<N_NODES / 4, 256, 0, stream>>>(csr_w, rowptr, dinv);
    norm_kernel<<<N_NODES / 4, 256, 0, stream>>>(csr_s, csr_w, dinv, rowptr);

    conv_f32_bf16<<<(N_NODES * 128 / 4) / 256, 256, 0, stream>>>(x, bufB, N_NODES * 128 / 4);
    conv_w_transpose<<<64, 256, 0, stream>>>(W1, Wt1, 128, 128);
    conv_w_transpose<<<64, 256, 0, stream>>>(W2, Wt2, 128, 128);
    conv_w_transpose<<<32, 256, 0, stream>>>(W3, Wt3, 128, 64);

    int gemm_blocks = (N_NODES / 16 + 3) / 4;  // 4 waves/block
    gemm_bf16<<<gemm_blocks, 256, 0, stream>>>(bufB, Wt1, bufA, 128);
    agg128<<<N_NODES / 4, 256, 0, stream>>>(bufA, rowptr, csr_s, csr_w, dinv, b1, bufB, 1);
    gemm_bf16<<<gemm_blocks, 256, 0, stream>>>(bufB, Wt2, bufA, 128);
    agg128<<<N_NODES / 4, 256, 0, stream>>>(bufA, rowptr, csr_s, csr_w, dinv, b2, bufB, 1);
    gemm_bf16<<<gemm_blocks, 256, 0, stream>>>(bufB, Wt3, bufA, 64);
    agg64_out<<<N_NODES / 4, 256, 0, stream>>>(bufA, rowptr, csr_s, csr_w, dinv, b3, (float*)d_out);
}

// Round 3
// 468.195 us; speedup vs baseline: 1.7231x; 1.2837x over previous
//
#include <hip/hip_runtime.h>
#include <hip/hip_bf16.h>
#include <stdint.h>

#define N_NODES 100000
#define N_EDGES 1600000
#define SCAN_NB 98   // ceil(100000/1024)

typedef __bf16 bf16x8 __attribute__((ext_vector_type(8)));
typedef float f32x4 __attribute__((ext_vector_type(4)));
typedef unsigned short u16;

__device__ __forceinline__ u16 f2b(float f) {
    uint32_t u = __builtin_bit_cast(uint32_t, f);
    uint32_t r = (u + 0x7fffu + ((u >> 16) & 1u)) >> 16;
    return (u16)r;
}
__device__ __forceinline__ float b2f(uint32_t lo16) {
    return __builtin_bit_cast(float, lo16 << 16);
}

// ---- pass 1: per-dst counts + per-edge rank (the ONLY atomic pass) ----
__global__ void rank_kernel(const int* __restrict__ dstp, int* __restrict__ cnt,
                            u16* __restrict__ rank) {
    int e = blockIdx.x * 256 + threadIdx.x;
    if (e >= N_EDGES) return;
    rank[e] = (u16)atomicAdd(&cnt[dstp[e]], 1);
}

// ---- 3-phase parallel exclusive scan: cnt -> rowptr ----
__global__ __launch_bounds__(1024) void scan1(const int* __restrict__ cnt,
                                              int* __restrict__ rowptr,
                                              int* __restrict__ bsum) {
    __shared__ int ws[16];
    int t = threadIdx.x;
    int i = blockIdx.x * 1024 + t;
    int lane = t & 63, wid = t >> 6;
    int v = (i < N_NODES) ? cnt[i] : 0;
    int x = v;
    #pragma unroll
    for (int off = 1; off < 64; off <<= 1) {
        int y = __shfl_up(x, off, 64);
        if (lane >= off) x += y;
    }
    if (lane == 63) ws[wid] = x;
    __syncthreads();
    int woff = 0;
    for (int j = 0; j < wid; j++) woff += ws[j];
    if (i < N_NODES) rowptr[i] = woff + x - v;
    if (t == 1023) bsum[blockIdx.x] = woff + x;
}

__global__ void scan2(const int* __restrict__ bsum, int* __restrict__ boff,
                      int* __restrict__ rowptr) {
    int lane = threadIdx.x;  // 64 threads, 1 block
    int carry = 0;
    for (int base = 0; base < SCAN_NB; base += 64) {
        int b = base + lane;
        int v = (b < SCAN_NB) ? bsum[b] : 0;
        int x = v;
        #pragma unroll
        for (int off = 1; off < 64; off <<= 1) {
            int y = __shfl_up(x, off, 64);
            if (lane >= off) x += y;
        }
        if (b < SCAN_NB) boff[b] = carry + x - v;
        carry += __shfl(x, 63, 64);
    }
    if (lane == 0) rowptr[N_NODES] = carry;
}

__global__ __launch_bounds__(1024) void scan3(int* __restrict__ rowptr,
                                              const int* __restrict__ boff) {
    int i = blockIdx.x * 1024 + threadIdx.x;
    if (i < N_NODES) rowptr[i] += boff[blockIdx.x];
}

// ---- pass 2: atomic-free CSR scatter, single 8-B store per edge ----
__global__ void scatter_kernel(const int* __restrict__ srcp, const int* __restrict__ dstp,
                               const float* __restrict__ w, const int* __restrict__ rowptr,
                               const u16* __restrict__ rank, int2* __restrict__ csr) {
    int e = blockIdx.x * 256 + threadIdx.x;
    if (e >= N_EDGES) return;
    int pos = rowptr[dstp[e]] + (int)rank[e];
    int2 m;
    m.x = srcp[e];
    m.y = __float_as_int(w[e]);
    csr[pos] = m;
}

// ---- deg via per-node contiguous reduction -> dinv ----
__global__ __launch_bounds__(256) void deg_kernel(const int2* __restrict__ csr,
                                                  const int* __restrict__ rowptr,
                                                  float* __restrict__ dinv) {
    int node = (blockIdx.x * 256 + threadIdx.x) >> 6;
    if (node >= N_NODES) return;
    int lane = threadIdx.x & 63;
    int jb = rowptr[node], je = rowptr[node + 1];
    float s = 0.f;
    for (int j = jb + lane; j < je; j += 64) s += __int_as_float(csr[j].y);
    #pragma unroll
    for (int off = 32; off; off >>= 1) s += __shfl_down(s, off, 64);
    if (lane == 0) dinv[node] = (s > 0.f) ? rsqrtf(fmaxf(s, 1e-30f)) : 0.f;
}

// ---- all three weights: fp32 [K x Dout] -> bf16 [Dout x K] transposed ----
__global__ void wconv_all(const float* __restrict__ W1, const float* __restrict__ W2,
                          const float* __restrict__ W3, u16* __restrict__ Wt1,
                          u16* __restrict__ Wt2, u16* __restrict__ Wt3) {
    int i = blockIdx.x * 256 + threadIdx.x;
    if (i < 16384) {                       // W1: 128x128
        int k = i >> 7, n = i & 127;
        Wt1[n * 128 + k] = f2b(W1[i]);
    } else if (i < 32768) {                // W2: 128x128
        int j = i - 16384;
        int k = j >> 7, n = j & 127;
        Wt2[n * 128 + k] = f2b(W2[j]);
    } else if (i < 40960) {                // W3: 128x64
        int j = i - 32768;
        int k = j >> 6, n = j & 63;
        Wt3[n * 128 + k] = f2b(W3[j]);
    }
}

// ---- GEMM layer1: A fp32 [N x 128] @ W -> bf16 C scaled by dinv[row] ----
__global__ __launch_bounds__(256) void gemm_f32A(const float* __restrict__ A,
                                                 const u16* __restrict__ Bt,
                                                 const float* __restrict__ dinv,
                                                 u16* __restrict__ C, int Dout) {
    int wid = (blockIdx.x * 256 + threadIdx.x) >> 6;
    if (wid >= N_NODES / 16) return;
    int lane = threadIdx.x & 63;
    int m = lane & 15;
    int k0 = (lane >> 4) * 8;
    int r0 = wid * 16;
    const float* ap = A + (size_t)(r0 + m) * 128 + k0;
    bf16x8 a[4];
    #pragma unroll
    for (int q = 0; q < 4; q++) {
        float4 lo = *(const float4*)(ap + q * 32);
        float4 hi = *(const float4*)(ap + q * 32 + 4);
        union { u16 s[8]; bf16x8 v; } u_;
        u_.s[0] = f2b(lo.x); u_.s[1] = f2b(lo.y); u_.s[2] = f2b(lo.z); u_.s[3] = f2b(lo.w);
        u_.s[4] = f2b(hi.x); u_.s[5] = f2b(hi.y); u_.s[6] = f2b(hi.z); u_.s[7] = f2b(hi.w);
        a[q] = u_.v;
    }
    int ntiles = Dout >> 4;
    int rbase = r0 + ((lane >> 4) << 2);
    float dv[4];
    #pragma unroll
    for (int i2 = 0; i2 < 4; i2++) dv[i2] = dinv[rbase + i2];
    for (int tn = 0; tn < ntiles; tn++) {
        const u16* bp = Bt + (size_t)(tn * 16 + m) * 128 + k0;
        f32x4 acc = {0.f, 0.f, 0.f, 0.f};
        acc = __builtin_amdgcn_mfma_f32_16x16x32_bf16(a[0], *(const bf16x8*)(bp + 0),  acc, 0, 0, 0);
        acc = __builtin_amdgcn_mfma_f32_16x16x32_bf16(a[1], *(const bf16x8*)(bp + 32), acc, 0, 0, 0);
        acc = __builtin_amdgcn_mfma_f32_16x16x32_bf16(a[2], *(const bf16x8*)(bp + 64), acc, 0, 0, 0);
        acc = __builtin_amdgcn_mfma_f32_16x16x32_bf16(a[3], *(const bf16x8*)(bp + 96), acc, 0, 0, 0);
        int col = tn * 16 + m;
        #pragma unroll
        for (int i2 = 0; i2 < 4; i2++)
            C[(size_t)(rbase + i2) * Dout + col] = f2b(acc[i2] * dv[i2]);
    }
}

// ---- GEMM layers 2/3: A bf16 [N x 128] @ W -> bf16 C scaled by dinv[row] ----
__global__ __launch_bounds__(256) void gemm_bf16(const u16* __restrict__ A,
                                                 const u16* __restrict__ Bt,
                                                 const float* __restrict__ dinv,
                                                 u16* __restrict__ C, int Dout) {
    int wid = (blockIdx.x * 256 + threadIdx.x) >> 6;
    if (wid >= N_NODES / 16) return;
    int lane = threadIdx.x & 63;
    int m = lane & 15;
    int k0 = (lane >> 4) * 8;
    int r0 = wid * 16;
    const u16* ap = A + (size_t)(r0 + m) * 128 + k0;
    bf16x8 a0 = *(const bf16x8*)(ap + 0);
    bf16x8 a1 = *(const bf16x8*)(ap + 32);
    bf16x8 a2 = *(const bf16x8*)(ap + 64);
    bf16x8 a3 = *(const bf16x8*)(ap + 96);
    int ntiles = Dout >> 4;
    int rbase = r0 + ((lane >> 4) << 2);
    float dv[4];
    #pragma unroll
    for (int i2 = 0; i2 < 4; i2++) dv[i2] = dinv[rbase + i2];
    for (int tn = 0; tn < ntiles; tn++) {
        const u16* bp = Bt + (size_t)(tn * 16 + m) * 128 + k0;
        f32x4 acc = {0.f, 0.f, 0.f, 0.f};
        acc = __builtin_amdgcn_mfma_f32_16x16x32_bf16(a0, *(const bf16x8*)(bp + 0),  acc, 0, 0, 0);
        acc = __builtin_amdgcn_mfma_f32_16x16x32_bf16(a1, *(const bf16x8*)(bp + 32), acc, 0, 0, 0);
        acc = __builtin_amdgcn_mfma_f32_16x16x32_bf16(a2, *(const bf16x8*)(bp + 64), acc, 0, 0, 0);
        acc = __builtin_amdgcn_mfma_f32_16x16x32_bf16(a3, *(const bf16x8*)(bp + 96), acc, 0, 0, 0);
        int col = tn * 16 + m;
        #pragma unroll
        for (int i2 = 0; i2 < 4; i2++)
            C[(size_t)(rbase + i2) * Dout + col] = f2b(acc[i2] * dv[i2]);
    }
}

// ---- aggregation dim=128: one wave/node; meta preloaded 64 edges/chunk,
//      broadcast via shfl; 8 gathers in flight (zero-weight padded) ----
__global__ __launch_bounds__(256) void agg128(const u16* __restrict__ H,
                                              const int* __restrict__ row_ptr,
                                              const int2* __restrict__ csr,
                                              const float* __restrict__ dinv,
                                              const float* __restrict__ bias,
                                              u16* __restrict__ out, int do_relu) {
    int node = (blockIdx.x * 256 + threadIdx.x) >> 6;
    if (node >= N_NODES) return;
    int lane = threadIdx.x & 63;
    int c = lane * 2;
    float a0 = 0.f, a1 = 0.f;
    int jb = row_ptr[node], je = row_ptr[node + 1];
    for (int base = jb; base < je; base += 64) {
        int n = je - base;
        if (n > 64) n = 64;
        int2 meta;
        if (base + lane < je) meta = csr[base + lane];
        else { meta.x = 0; meta.y = 0; }
        for (int e = 0; e < n; e += 8) {
            int s[8]; float w[8];
            #pragma unroll
            for (int u = 0; u < 8; u++) {
                int idx = e + u;
                int sv = __shfl(meta.x, idx, 64);
                int wv = __shfl(meta.y, idx, 64);
                bool ok = idx < n;
                s[u] = ok ? sv : 0;
                w[u] = ok ? __int_as_float(wv) : 0.f;
            }
            uint32_t p[8];
            #pragma unroll
            for (int u = 0; u < 8; u++)
                p[u] = *(const uint32_t*)(H + (size_t)s[u] * 128 + c);
            #pragma unroll
            for (int u = 0; u < 8; u++) {
                a0 += w[u] * b2f(p[u] & 0xffffu);
                a1 += w[u] * b2f(p[u] >> 16);
            }
        }
    }
    float dv = dinv[node];
    a0 = dv * a0 + bias[c];
    a1 = dv * a1 + bias[c + 1];
    if (do_relu) { a0 = fmaxf(a0, 0.f); a1 = fmaxf(a1, 0.f); }
    uint32_t o = (uint32_t)f2b(a0) | ((uint32_t)f2b(a1) << 16);
    *(uint32_t*)(out + (size_t)node * 128 + c) = o;
}

// ---- final aggregation dim=64: 2 nodes/wave (32 lanes each), fp32 out x2 ----
__global__ __launch_bounds__(256) void agg64_out(const u16* __restrict__ H,
                                                 const int* __restrict__ row_ptr,
                                                 const int2* __restrict__ csr,
                                                 const float* __restrict__ dinv,
                                                 const float* __restrict__ bias,
                                                 float* __restrict__ out) {
    int wv = (blockIdx.x * 256 + threadIdx.x) >> 6;
    int node = wv * 2 + ((threadIdx.x >> 5) & 1);
    if (node >= N_NODES) return;
    int lane = threadIdx.x & 31;
    int c = lane * 2;
    float a0 = 0.f, a1 = 0.f;
    int jb = row_ptr[node], je = row_ptr[node + 1];
    for (int base = jb; base < je; base += 32) {
        int n = je - base;
        if (n > 32) n = 32;
        int2 meta;
        if (base + lane < je) meta = csr[base + lane];
        else { meta.x = 0; meta.y = 0; }
        for (int e = 0; e < n; e += 8) {
            int s[8]; float w[8];
            #pragma unroll
            for (int u = 0; u < 8; u++) {
                int idx = e + u;
                int sv = __shfl(meta.x, idx, 32);
                int wv2 = __shfl(meta.y, idx, 32);
                bool ok = idx < n;
                s[u] = ok ? sv : 0;
                w[u] = ok ? __int_as_float(wv2) : 0.f;
            }
            uint32_t p[8];
            #pragma unroll
            for (int u = 0; u < 8; u++)
                p[u] = *(const uint32_t*)(H + (size_t)s[u] * 64 + c);
            #pragma unroll
            for (int u = 0; u < 8; u++) {
                a0 += w[u] * b2f(p[u] & 0xffffu);
                a1 += w[u] * b2f(p[u] >> 16);
            }
        }
    }
    float dv = dinv[node];
    a0 = dv * a0 + bias[c];
    a1 = dv * a1 + bias[c + 1];
    size_t o = (size_t)node * 64 + c;
    float2 r; r.x = a0; r.y = a1;
    *(float2*)(out + o) = r;
    *(float2*)(out + (size_t)N_NODES * 64 + o) = r;
}

extern "C" void kernel_launch(void* const* d_in, const int* in_sizes, int n_in,
                              void* d_out, int out_size, void* d_ws, size_t ws_size,
                              hipStream_t stream) {
    const float* x  = (const float*)d_in[0];
    const int* eidx = (const int*)d_in[1];
    const float* ew = (const float*)d_in[2];
    const float* W1 = (const float*)d_in[3];
    const float* b1 = (const float*)d_in[4];
    const float* W2 = (const float*)d_in[5];
    const float* b2 = (const float*)d_in[6];
    const float* W3 = (const float*)d_in[7];
    const float* b3 = (const float*)d_in[8];
    const int* srcp = eidx;
    const int* dstp = eidx + N_EDGES;

    char* ws = (char*)d_ws;
    size_t off = 0;
    auto alloc = [&](size_t bytes) -> void* {
        void* p = ws + off;
        off += (bytes + 255) & ~(size_t)255;
        return p;
    };
    int*   cnt    = (int*)  alloc((size_t)N_NODES * 4);        // zeroed below
    int*   rowptr = (int*)  alloc((size_t)(N_NODES + 1) * 4);
    int*   bsum   = (int*)  alloc(SCAN_NB * 4);
    int*   boff   = (int*)  alloc(SCAN_NB * 4);
    u16*   rank   = (u16*)  alloc((size_t)N_EDGES * 2);
    int2*  csr    = (int2*) alloc((size_t)N_EDGES * 8);
    float* dinv   = (float*)alloc((size_t)N_NODES * 4);
    u16*   Wt1    = (u16*)  alloc(128 * 128 * 2);
    u16*   Wt2    = (u16*)  alloc(128 * 128 * 2);
    u16*   Wt3    = (u16*)  alloc(128 * 64 * 2);
    u16*   bufA   = (u16*)  alloc((size_t)N_NODES * 128 * 2);
    u16*   bufB   = (u16*)  alloc((size_t)N_NODES * 128 * 2);

    hipMemsetAsync(cnt, 0, (size_t)N_NODES * 4, stream);

    rank_kernel<<<N_EDGES / 256, 256, 0, stream>>>(dstp, cnt, rank);
    scan1<<<SCAN_NB, 1024, 0, stream>>>(cnt, rowptr, bsum);
    scan2<<<1, 64, 0, stream>>>(bsum, boff, rowptr);
    scan3<<<SCAN_NB, 1024, 0, stream>>>(rowptr, boff);
    scatter_kernel<<<N_EDGES / 256, 256, 0, stream>>>(srcp, dstp, ew, rowptr, rank, csr);
    deg_kernel<<<N_NODES / 4, 256, 0, stream>>>(csr, rowptr, dinv);
    wconv_all<<<160, 256, 0, stream>>>(W1, W2, W3, Wt1, Wt2, Wt3);

    int gemm_blocks = (N_NODES / 16 + 3) / 4;  // 4 waves/block
    gemm_f32A<<<gemm_blocks, 256, 0, stream>>>(x, Wt1, dinv, bufA, 128);
    agg128<<<N_NODES / 4, 256, 0, stream>>>(bufA, rowptr, csr, dinv, b1, bufB, 1);
    gemm_bf16<<<gemm_blocks, 256, 0, stream>>>(bufB, Wt2, dinv, bufA, 128);
    agg128<<<N_NODES / 4, 256, 0, stream>>>(bufA, rowptr, csr, dinv, b2, bufB, 1);
    gemm_bf16<<<gemm_blocks, 256, 0, stream>>>(bufB, Wt3, dinv, bufA, 64);
    agg64_out<<<N_NODES / 8, 256, 0, stream>>>(bufA, rowptr, csr, dinv, b3, (float*)d_out);
}

// Round 4
// 422.288 us; speedup vs baseline: 1.9104x; 1.1087x over previous
//
#include <hip/hip_runtime.h>
#include <hip/hip_bf16.h>
#include <stdint.h>

#define N_NODES 100000
#define N_EDGES 1600000
#define NB_P 400      // partition blocks
#define EPP 4000      // edges per partition block (400*4000 = 1.6M)
#define NBUCK 391     // ceil(100000/256) buckets of 256 dst nodes

typedef __bf16 bf16x8 __attribute__((ext_vector_type(8)));
typedef float f32x4 __attribute__((ext_vector_type(4)));
typedef unsigned short u16;

__device__ __forceinline__ u16 f2b(float f) {
    uint32_t u = __builtin_bit_cast(uint32_t, f);
    uint32_t r = (u + 0x7fffu + ((u >> 16) & 1u)) >> 16;
    return (u16)r;
}
__device__ __forceinline__ float b2f(uint32_t lo16) {
    return __builtin_bit_cast(float, lo16 << 16);
}

// ---- A: per-(bucket,block) histogram, LDS atomics only ----
__global__ __launch_bounds__(256) void part_hist(const int* __restrict__ dstp,
                                                 int* __restrict__ hist) {
    __shared__ int h[NBUCK];
    int t = threadIdx.x, p = blockIdx.x;
    for (int b = t; b < NBUCK; b += 256) h[b] = 0;
    __syncthreads();
    int e0 = p * EPP;
    for (int i = t; i < EPP; i += 256)
        atomicAdd(&h[dstp[e0 + i] >> 8], 1);
    __syncthreads();
    for (int b = t; b < NBUCK; b += 256) hist[b * NB_P + p] = h[b];
}

// ---- B1: per-bucket totals (one wave per bucket) ----
__global__ void bucket_totals(const int* __restrict__ hist, int* __restrict__ totals) {
    int w = (blockIdx.x * 256 + threadIdx.x) >> 6;
    if (w >= NBUCK) return;
    int lane = threadIdx.x & 63;
    int s = 0;
    for (int p = lane; p < NB_P; p += 64) s += hist[w * NB_P + p];
    #pragma unroll
    for (int off = 32; off; off >>= 1) s += __shfl_down(s, off, 64);
    if (lane == 0) totals[w] = s;
}

// ---- B2: exclusive scan of bucket totals -> base (single wave) ----
__global__ void bucket_scan(const int* __restrict__ totals, int* __restrict__ base,
                            int* __restrict__ rowptr) {
    int lane = threadIdx.x;  // 64 threads
    int carry = 0;
    for (int s0 = 0; s0 < NBUCK; s0 += 64) {
        int b = s0 + lane;
        int v = (b < NBUCK) ? totals[b] : 0;
        int x = v;
        #pragma unroll
        for (int off = 1; off < 64; off <<= 1) {
            int y = __shfl_up(x, off, 64);
            if (lane >= off) x += y;
        }
        if (b < NBUCK) base[b] = carry + x - v;
        carry += __shfl(x, 63, 64);
    }
    if (lane == 0) { base[NBUCK] = carry; rowptr[N_NODES] = carry; }
}

// ---- B3: per-bucket exclusive scan across partition blocks -> off ----
__global__ void bucket_off(const int* __restrict__ hist, const int* __restrict__ base,
                           int* __restrict__ off) {
    int w = (blockIdx.x * 256 + threadIdx.x) >> 6;
    if (w >= NBUCK) return;
    int lane = threadIdx.x & 63;
    int run = base[w];
    for (int s0 = 0; s0 < NB_P; s0 += 64) {
        int p = s0 + lane;
        int v = (p < NB_P) ? hist[w * NB_P + p] : 0;
        int x = v;
        #pragma unroll
        for (int o = 1; o < 64; o <<= 1) {
            int y = __shfl_up(x, o, 64);
            if (lane >= o) x += y;
        }
        if (p < NB_P) off[w * NB_P + p] = run + x - v;
        run += __shfl(x, 63, 64);
    }
}

// ---- C: partition scatter via LDS cursors (no global atomics) ----
__global__ __launch_bounds__(256) void part_scatter(const int* __restrict__ srcp,
                                                    const int* __restrict__ dstp,
                                                    const float* __restrict__ ew,
                                                    const int* __restrict__ off,
                                                    int4* __restrict__ part) {
    __shared__ int cur[NBUCK];
    int t = threadIdx.x, p = blockIdx.x;
    for (int b = t; b < NBUCK; b += 256) cur[b] = off[b * NB_P + p];
    __syncthreads();
    int e0 = p * EPP;
    for (int i = t; i < EPP; i += 256) {
        int e = e0 + i;
        int s = srcp[e], d = dstp[e];
        float w = ew[e];
        int pos = atomicAdd(&cur[d >> 8], 1);
        int4 E;
        E.x = s; E.y = d; E.z = __float_as_int(w); E.w = 0;
        part[pos] = E;
    }
}

// ---- D: per-bucket CSR build + rowptr + dinv (absorbs deg_kernel) ----
__global__ __launch_bounds__(256) void bucket_build(const int4* __restrict__ part,
                                                    const int* __restrict__ base,
                                                    int* __restrict__ rowptr,
                                                    float* __restrict__ dinv,
                                                    int2* __restrict__ csr) {
    __shared__ int h[256];
    __shared__ float dw[256];
    __shared__ int cur[256];
    __shared__ int wsum[4];
    int t = threadIdx.x, b = blockIdx.x;
    h[t] = 0; dw[t] = 0.f;
    __syncthreads();
    int jb = base[b], je = base[b + 1];
    for (int i = jb + t; i < je; i += 256) {
        int4 E = part[i];
        int li = E.y & 255;
        atomicAdd(&h[li], 1);
        atomicAdd(&dw[li], __int_as_float(E.z));
    }
    __syncthreads();
    int lane = t & 63, wid = t >> 6;
    int v = h[t];
    int x = v;
    #pragma unroll
    for (int o = 1; o < 64; o <<= 1) {
        int y = __shfl_up(x, o, 64);
        if (lane >= o) x += y;
    }
    if (lane == 63) wsum[wid] = x;
    __syncthreads();
    int woff = 0;
    for (int j = 0; j < wid; j++) woff += wsum[j];
    int excl = jb + woff + x - v;
    int node = b * 256 + t;
    if (node < N_NODES) {
        rowptr[node] = excl;
        float s = dw[t];
        dinv[node] = (s > 0.f) ? rsqrtf(fmaxf(s, 1e-30f)) : 0.f;
    }
    cur[t] = excl;
    __syncthreads();
    for (int i = jb + t; i < je; i += 256) {
        int4 E = part[i];
        int li = E.y & 255;
        int pos = atomicAdd(&cur[li], 1);
        int2 c;
        c.x = E.x; c.y = E.z;
        csr[pos] = c;
    }
}

// ---- all three weights: fp32 [K x Dout] -> bf16 [Dout x K] transposed ----
__global__ void wconv_all(const float* __restrict__ W1, const float* __restrict__ W2,
                          const float* __restrict__ W3, u16* __restrict__ Wt1,
                          u16* __restrict__ Wt2, u16* __restrict__ Wt3) {
    int i = blockIdx.x * 256 + threadIdx.x;
    if (i < 16384) {                       // W1: 128x128
        int k = i >> 7, n = i & 127;
        Wt1[n * 128 + k] = f2b(W1[i]);
    } else if (i < 32768) {                // W2: 128x128
        int j = i - 16384;
        int k = j >> 7, n = j & 127;
        Wt2[n * 128 + k] = f2b(W2[j]);
    } else if (i < 40960) {                // W3: 128x64
        int j = i - 32768;
        int k = j >> 6, n = j & 63;
        Wt3[n * 128 + k] = f2b(W3[j]);
    }
}

// ---- GEMM layer1: A fp32 [N x 128] @ W -> bf16 C scaled by dinv[row] ----
__global__ __launch_bounds__(256) void gemm_f32A(const float* __restrict__ A,
                                                 const u16* __restrict__ Bt,
                                                 const float* __restrict__ dinv,
                                                 u16* __restrict__ C, int Dout) {
    int wid = (blockIdx.x * 256 + threadIdx.x) >> 6;
    if (wid >= N_NODES / 16) return;
    int lane = threadIdx.x & 63;
    int m = lane & 15;
    int k0 = (lane >> 4) * 8;
    int r0 = wid * 16;
    const float* ap = A + (size_t)(r0 + m) * 128 + k0;
    bf16x8 a[4];
    #pragma unroll
    for (int q = 0; q < 4; q++) {
        float4 lo = *(const float4*)(ap + q * 32);
        float4 hi = *(const float4*)(ap + q * 32 + 4);
        union { u16 s[8]; bf16x8 v; } u_;
        u_.s[0] = f2b(lo.x); u_.s[1] = f2b(lo.y); u_.s[2] = f2b(lo.z); u_.s[3] = f2b(lo.w);
        u_.s[4] = f2b(hi.x); u_.s[5] = f2b(hi.y); u_.s[6] = f2b(hi.z); u_.s[7] = f2b(hi.w);
        a[q] = u_.v;
    }
    int ntiles = Dout >> 4;
    int rbase = r0 + ((lane >> 4) << 2);
    float dv[4];
    #pragma unroll
    for (int i2 = 0; i2 < 4; i2++) dv[i2] = dinv[rbase + i2];
    for (int tn = 0; tn < ntiles; tn++) {
        const u16* bp = Bt + (size_t)(tn * 16 + m) * 128 + k0;
        f32x4 acc = {0.f, 0.f, 0.f, 0.f};
        acc = __builtin_amdgcn_mfma_f32_16x16x32_bf16(a[0], *(const bf16x8*)(bp + 0),  acc, 0, 0, 0);
        acc = __builtin_amdgcn_mfma_f32_16x16x32_bf16(a[1], *(const bf16x8*)(bp + 32), acc, 0, 0, 0);
        acc = __builtin_amdgcn_mfma_f32_16x16x32_bf16(a[2], *(const bf16x8*)(bp + 64), acc, 0, 0, 0);
        acc = __builtin_amdgcn_mfma_f32_16x16x32_bf16(a[3], *(const bf16x8*)(bp + 96), acc, 0, 0, 0);
        int col = tn * 16 + m;
        #pragma unroll
        for (int i2 = 0; i2 < 4; i2++)
            C[(size_t)(rbase + i2) * Dout + col] = f2b(acc[i2] * dv[i2]);
    }
}

// ---- GEMM layers 2/3: A bf16 [N x 128] @ W -> bf16 C scaled by dinv[row] ----
__global__ __launch_bounds__(256) void gemm_bf16(const u16* __restrict__ A,
                                                 const u16* __restrict__ Bt,
                                                 const float* __restrict__ dinv,
                                                 u16* __restrict__ C, int Dout) {
    int wid = (blockIdx.x * 256 + threadIdx.x) >> 6;
    if (wid >= N_NODES / 16) return;
    int lane = threadIdx.x & 63;
    int m = lane & 15;
    int k0 = (lane >> 4) * 8;
    int r0 = wid * 16;
    const u16* ap = A + (size_t)(r0 + m) * 128 + k0;
    bf16x8 a0 = *(const bf16x8*)(ap + 0);
    bf16x8 a1 = *(const bf16x8*)(ap + 32);
    bf16x8 a2 = *(const bf16x8*)(ap + 64);
    bf16x8 a3 = *(const bf16x8*)(ap + 96);
    int ntiles = Dout >> 4;
    int rbase = r0 + ((lane >> 4) << 2);
    float dv[4];
    #pragma unroll
    for (int i2 = 0; i2 < 4; i2++) dv[i2] = dinv[rbase + i2];
    for (int tn = 0; tn < ntiles; tn++) {
        const u16* bp = Bt + (size_t)(tn * 16 + m) * 128 + k0;
        f32x4 acc = {0.f, 0.f, 0.f, 0.f};
        acc = __builtin_amdgcn_mfma_f32_16x16x32_bf16(a0, *(const bf16x8*)(bp + 0),  acc, 0, 0, 0);
        acc = __builtin_amdgcn_mfma_f32_16x16x32_bf16(a1, *(const bf16x8*)(bp + 32), acc, 0, 0, 0);
        acc = __builtin_amdgcn_mfma_f32_16x16x32_bf16(a2, *(const bf16x8*)(bp + 64), acc, 0, 0, 0);
        acc = __builtin_amdgcn_mfma_f32_16x16x32_bf16(a3, *(const bf16x8*)(bp + 96), acc, 0, 0, 0);
        int col = tn * 16 + m;
        #pragma unroll
        for (int i2 = 0; i2 < 4; i2++)
            C[(size_t)(rbase + i2) * Dout + col] = f2b(acc[i2] * dv[i2]);
    }
}

// ---- aggregation dim=128: one wave/node; shfl-broadcast meta; 8 in flight ----
__global__ __launch_bounds__(256) void agg128(const u16* __restrict__ H,
                                              const int* __restrict__ row_ptr,
                                              const int2* __restrict__ csr,
                                              const float* __restrict__ dinv,
                                              const float* __restrict__ bias,
                                              u16* __restrict__ out, int do_relu) {
    int node = (blockIdx.x * 256 + threadIdx.x) >> 6;
    if (node >= N_NODES) return;
    int lane = threadIdx.x & 63;
    int c = lane * 2;
    float a0 = 0.f, a1 = 0.f;
    int jb = row_ptr[node], je = row_ptr[node + 1];
    for (int base = jb; base < je; base += 64) {
        int n = je - base;
        if (n > 64) n = 64;
        int2 meta;
        if (base + lane < je) meta = csr[base + lane];
        else { meta.x = 0; meta.y = 0; }
        for (int e = 0; e < n; e += 8) {
            int s[8]; float w[8];
            #pragma unroll
            for (int u = 0; u < 8; u++) {
                int idx = e + u;
                int sv = __shfl(meta.x, idx, 64);
                int wv = __shfl(meta.y, idx, 64);
                bool ok = idx < n;
                s[u] = ok ? sv : 0;
                w[u] = ok ? __int_as_float(wv) : 0.f;
            }
            uint32_t p[8];
            #pragma unroll
            for (int u = 0; u < 8; u++)
                p[u] = *(const uint32_t*)(H + (size_t)s[u] * 128 + c);
            #pragma unroll
            for (int u = 0; u < 8; u++) {
                a0 += w[u] * b2f(p[u] & 0xffffu);
                a1 += w[u] * b2f(p[u] >> 16);
            }
        }
    }
    float dv = dinv[node];
    a0 = dv * a0 + bias[c];
    a1 = dv * a1 + bias[c + 1];
    if (do_relu) { a0 = fmaxf(a0, 0.f); a1 = fmaxf(a1, 0.f); }
    uint32_t o = (uint32_t)f2b(a0) | ((uint32_t)f2b(a1) << 16);
    *(uint32_t*)(out + (size_t)node * 128 + c) = o;
}

// ---- final aggregation dim=64: 2 nodes/wave, fp32 out written twice ----
__global__ __launch_bounds__(256) void agg64_out(const u16* __restrict__ H,
                                                 const int* __restrict__ row_ptr,
                                                 const int2* __restrict__ csr,
                                                 const float* __restrict__ dinv,
                                                 const float* __restrict__ bias,
                                                 float* __restrict__ out) {
    int wv = (blockIdx.x * 256 + threadIdx.x) >> 6;
    int node = wv * 2 + ((threadIdx.x >> 5) & 1);
    if (node >= N_NODES) return;
    int lane = threadIdx.x & 31;
    int c = lane * 2;
    float a0 = 0.f, a1 = 0.f;
    int jb = row_ptr[node], je = row_ptr[node + 1];
    for (int base = jb; base < je; base += 32) {
        int n = je - base;
        if (n > 32) n = 32;
        int2 meta;
        if (base + lane < je) meta = csr[base + lane];
        else { meta.x = 0; meta.y = 0; }
        for (int e = 0; e < n; e += 8) {
            int s[8]; float w[8];
            #pragma unroll
            for (int u = 0; u < 8; u++) {
                int idx = e + u;
                int sv = __shfl(meta.x, idx, 32);
                int wv2 = __shfl(meta.y, idx, 32);
                bool ok = idx < n;
                s[u] = ok ? sv : 0;
                w[u] = ok ? __int_as_float(wv2) : 0.f;
            }
            uint32_t p[8];
            #pragma unroll
            for (int u = 0; u < 8; u++)
                p[u] = *(const uint32_t*)(H + (size_t)s[u] * 64 + c);
            #pragma unroll
            for (int u = 0; u < 8; u++) {
                a0 += w[u] * b2f(p[u] & 0xffffu);
                a1 += w[u] * b2f(p[u] >> 16);
            }
        }
    }
    float dv = dinv[node];
    a0 = dv * a0 + bias[c];
    a1 = dv * a1 + bias[c + 1];
    size_t o = (size_t)node * 64 + c;
    float2 r; r.x = a0; r.y = a1;
    *(float2*)(out + o) = r;
    *(float2*)(out + (size_t)N_NODES * 64 + o) = r;
}

extern "C" void kernel_launch(void* const* d_in, const int* in_sizes, int n_in,
                              void* d_out, int out_size, void* d_ws, size_t ws_size,
                              hipStream_t stream) {
    const float* x  = (const float*)d_in[0];
    const int* eidx = (const int*)d_in[1];
    const float* ew = (const float*)d_in[2];
    const float* W1 = (const float*)d_in[3];
    const float* b1 = (const float*)d_in[4];
    const float* W2 = (const float*)d_in[5];
    const float* b2 = (const float*)d_in[6];
    const float* W3 = (const float*)d_in[7];
    const float* b3 = (const float*)d_in[8];
    const int* srcp = eidx;
    const int* dstp = eidx + N_EDGES;

    char* ws = (char*)d_ws;
    size_t off_ = 0;
    auto alloc = [&](size_t bytes) -> void* {
        void* p = ws + off_;
        off_ += (bytes + 255) & ~(size_t)255;
        return p;
    };
    int*   hist   = (int*)  alloc((size_t)NBUCK * NB_P * 4);
    int*   offm   = (int*)  alloc((size_t)NBUCK * NB_P * 4);
    int*   totals = (int*)  alloc((size_t)NBUCK * 4);
    int*   base   = (int*)  alloc((size_t)(NBUCK + 1) * 4);
    int*   rowptr = (int*)  alloc((size_t)(N_NODES + 1) * 4);
    int2*  csr    = (int2*) alloc((size_t)N_EDGES * 8);
    float* dinv   = (float*)alloc((size_t)N_NODES * 4);
    u16*   Wt1    = (u16*)  alloc(128 * 128 * 2);
    u16*   Wt2    = (u16*)  alloc(128 * 128 * 2);
    u16*   Wt3    = (u16*)  alloc(128 * 64 * 2);
    u16*   bufA   = (u16*)  alloc((size_t)N_NODES * 128 * 2);
    u16*   bufB   = (u16*)  alloc((size_t)N_NODES * 128 * 2);
    // part aliases bufA: consumed by bucket_build before gemm1 writes bufA.
    int4*  part   = (int4*)bufA;   // 1.6M * 16B = 25.6MB == bufA size

    part_hist<<<NB_P, 256, 0, stream>>>(dstp, hist);
    bucket_totals<<<(NBUCK + 3) / 4, 256, 0, stream>>>(hist, totals);
    bucket_scan<<<1, 64, 0, stream>>>(totals, base, rowptr);
    bucket_off<<<(NBUCK + 3) / 4, 256, 0, stream>>>(hist, base, offm);
    part_scatter<<<NB_P, 256, 0, stream>>>(srcp, dstp, ew, offm, part);
    bucket_build<<<NBUCK, 256, 0, stream>>>(part, base, rowptr, dinv, csr);
    wconv_all<<<160, 256, 0, stream>>>(W1, W2, W3, Wt1, Wt2, Wt3);

    int gemm_blocks = (N_NODES / 16 + 3) / 4;  // 4 waves/block
    gemm_f32A<<<gemm_blocks, 256, 0, stream>>>(x, Wt1, dinv, bufA, 128);
    agg128<<<N_NODES / 4, 256, 0, stream>>>(bufA, rowptr, csr, dinv, b1, bufB, 1);
    gemm_bf16<<<gemm_blocks, 256, 0, stream>>>(bufB, Wt2, dinv, bufA, 128);
    agg128<<<N_NODES / 4, 256, 0, stream>>>(bufA, rowptr, csr, dinv, b2, bufB, 1);
    gemm_bf16<<<gemm_blocks, 256, 0, stream>>>(bufB, Wt3, dinv, bufA, 64);
    agg64_out<<<N_NODES / 8, 256, 0, stream>>>(bufA, rowptr, csr, dinv, b3, (float*)d_out);
}